// Round 1
// baseline (231.474 us; speedup 1.0000x reference)
//
#include <hip/hip_runtime.h>

#define G 64

__global__ void zero_out_kernel(float* out) {
    if (threadIdx.x == 0 && blockIdx.x == 0) out[0] = 0.0f;
}

__global__ __launch_bounds__(256) void cad_deform_loss_kernel(
    const float* __restrict__ V,      // [N,3]
    const int2*  __restrict__ E,      // [NE,2] as int2
    const float* __restrict__ grid,   // [64,64,64]
    const float* __restrict__ rest,   // [NE]
    float* __restrict__ out,
    int N, int NE)
{
    const int tid    = blockIdx.x * blockDim.x + threadIdx.x;
    const int stride = gridDim.x * blockDim.x;

    float acc = 0.0f;

    // ---- Part 1: trilinear distance loss over N points ----
    for (int i = tid; i < N; i += stride) {
        float x = V[3*i + 0];
        float y = V[3*i + 1];
        float z = V[3*i + 2];
        float px = x * 63.0f, py = y * 63.0f, pz = z * 63.0f;
        int x0 = (int)floorf(px);
        int y0 = (int)floorf(py);
        int z0 = (int)floorf(pz);
        x0 = min(max(x0, 0), 62);
        y0 = min(max(y0, 0), 62);
        z0 = min(max(z0, 0), 62);
        float fx = px - (float)x0;
        float fy = py - (float)y0;
        float fz = pz - (float)z0;

        int base = (x0 * G + y0) * G + z0;
        // grid[x,y,z] at base; +1 => z+1 ; +G => y+1 ; +G*G => x+1
        float g000 = grid[base];
        float g001 = grid[base + 1];
        float g010 = grid[base + G];
        float g011 = grid[base + G + 1];
        float g100 = grid[base + G*G];
        float g101 = grid[base + G*G + 1];
        float g110 = grid[base + G*G + G];
        float g111 = grid[base + G*G + G + 1];

        float c00 = g000 + (g100 - g000) * fx;
        float c01 = g001 + (g101 - g001) * fx;
        float c10 = g010 + (g110 - g010) * fx;
        float c11 = g011 + (g111 - g011) * fx;
        float c0  = c00 + (c10 - c00) * fy;
        float c1  = c01 + (c11 - c01) * fy;
        float d   = c0 + (c1 - c0) * fz;

        acc += 0.5f * d * d;
    }

    // ---- Part 2: edge rest-length loss over NE edges ----
    for (int i = tid; i < NE; i += stride) {
        int2 e = E[i];
        int a = e.x, b = e.y;
        float dx = V[3*a + 0] - V[3*b + 0];
        float dy = V[3*a + 1] - V[3*b + 1];
        float dz = V[3*a + 2] - V[3*b + 2];
        float elen = sqrtf(dx*dx + dy*dy + dz*dz + 1e-12f);
        float r = elen - rest[i];
        acc += 0.5f * r * r;
    }

    // ---- Block reduction: wave64 shuffle -> LDS -> one atomic ----
    for (int off = 32; off > 0; off >>= 1)
        acc += __shfl_down(acc, off, 64);

    __shared__ float wsum[4];  // 256 threads / 64 lanes
    const int lane = threadIdx.x & 63;
    const int wid  = threadIdx.x >> 6;
    if (lane == 0) wsum[wid] = acc;
    __syncthreads();
    if (threadIdx.x == 0) {
        float s = wsum[0] + wsum[1] + wsum[2] + wsum[3];
        atomicAdd(out, s);
    }
}

extern "C" void kernel_launch(void* const* d_in, const int* in_sizes, int n_in,
                              void* d_out, int out_size, void* d_ws, size_t ws_size,
                              hipStream_t stream) {
    const float* V    = (const float*)d_in[0];   // src_V  [N,3]
    // d_in[1] = src_F (unused by the reference)
    const int2*  E    = (const int2*)d_in[2];    // src_E  [NE,2] int32
    const float* grid = (const float*)d_in[3];   // dist_grid [64,64,64]
    const float* rest = (const float*)d_in[4];   // rest_len [NE]
    float* out = (float*)d_out;

    const int N  = in_sizes[0] / 3;
    const int NE = in_sizes[2] / 2;

    zero_out_kernel<<<1, 64, 0, stream>>>(out);

    const int block = 256;
    const int grid_blocks = 2048;  // grid-stride; ~8 blocks/CU launch budget
    cad_deform_loss_kernel<<<grid_blocks, block, 0, stream>>>(
        V, E, grid, rest, out, N, NE);
}